// Round 12
// baseline (121.354 us; speedup 1.0000x reference)
//
#include <hip/hip_runtime.h>
#include <stdint.h>

#define HW 3136
#define IMGW 56
#define NIMG 32

static __device__ __forceinline__ int dot4i8(int a, int b, int c) {
#if __has_builtin(__builtin_amdgcn_sdot4)
  return __builtin_amdgcn_sdot4(a, b, c, false);
#else
  c += (int)(int8_t)(a      ) * (int)(int8_t)(b      );
  c += (int)(int8_t)(a >>  8) * (int)(int8_t)(b >>  8);
  c += (int)(int8_t)(a >> 16) * (int)(int8_t)(b >> 16);
  c += (int)(int8_t)(a >> 24) * (int)(int8_t)(b >> 24);
  return c;
#endif
}

// BN: round((alpha*acc + off) * 2^-10), clamp to [-128,127]. Exact f32 ops,
// no contraction (matches numpy mul/add/round-half-even chain bit-exactly).
static __device__ __forceinline__ float bnq(float alpha, float off, int acc) {
  float t = __fmul_rn(alpha, (float)acc);
  t = __fadd_rn(t, off);
  t = __fmul_rn(t, 0x1p-10f);
  float r = rintf(t);
  return fminf(fmaxf(r, -128.0f), 127.0f);
}

// ---------------- prep: pack weights + fold BN constants ----------------
__global__ void prep_kernel(
    const int* __restrict__ s1, const int* __restrict__ m1,
    const float* __restrict__ a1, const float* __restrict__ b1, const int* __restrict__ q1,
    const int* __restrict__ s2, const int* __restrict__ m2,
    const float* __restrict__ a2, const float* __restrict__ b2, const int* __restrict__ q2,
    const int* __restrict__ s3, const int* __restrict__ m3,
    const float* __restrict__ a3, const float* __restrict__ b3, const int* __restrict__ q3,
    int* __restrict__ w1p, int* __restrict__ w2p, int* __restrict__ w3p,
    float* __restrict__ a1p, float* __restrict__ o1p,
    float* __restrict__ a2p, float* __restrict__ o2p,
    float* __restrict__ a3p, float* __restrict__ o3p)
{
  int t = blockIdx.x * blockDim.x + threadIdx.x;
  int nthr = gridDim.x * blockDim.x;

  // w1p[cg*64 + co] packs input channels cg*4..cg*4+3 for output co (conv1: 64x256)
  for (int i = t; i < 64 * 64; i += nthr) {
    int cg = i >> 6, co = i & 63;
    int p = 0;
    for (int j = 0; j < 4; ++j) {
      int ci = cg * 4 + j;
      int idx = co * 256 + ci;
      int w = m1[idx] * (1 << s1[idx]);
      p |= (w & 0xFF) << (8 * j);
    }
    w1p[i] = p;
  }
  // w2p layout: i = ((s*9+tap)*16+cg)*16 + cc*4 + j
  for (int i = t; i < 4 * 9 * 16 * 16; i += nthr) {
    int j = i & 3;
    int cc = (i >> 2) & 3;
    int cg = (i >> 4) & 15;
    int rest = i >> 8;        // s*9 + tap
    int tap = rest % 9;
    int s = rest / 9;
    int co = s * 16 + cc * 4 + j;
    int ky = tap / 3, kx = tap % 3;
    int p = 0;
    for (int jj = 0; jj < 4; ++jj) {
      int ci = cg * 4 + jj;
      int idx = ((co * 64 + ci) * 3 + ky) * 3 + kx;
      int w = m2[idx] * (1 << s2[idx]);
      p |= (w & 0xFF) << (8 * jj);
    }
    w2p[i] = p;
  }
  // w3p[(co4*16+cg)*4 + j]
  for (int i = t; i < 64 * 16 * 4; i += nthr) {
    int j = i & 3;
    int cg = (i >> 2) & 15;
    int co4 = i >> 6;
    int co = co4 * 4 + j;
    int p = 0;
    for (int jj = 0; jj < 4; ++jj) {
      int ci = cg * 4 + jj;
      int idx = co * 64 + ci;
      int w = m3[idx] * (1 << s3[idx]);
      p |= (w & 0xFF) << (8 * jj);
    }
    w3p[i] = p;
  }
  for (int i = t; i < 64; i += nthr) {
    a1p[i] = a1[i];
    o1p[i] = __fmul_rn(b1[i], exp2f((float)q1[i] + 10.0f));
    a2p[i] = a2[i];
    o2p[i] = __fmul_rn(b2[i], exp2f((float)q2[i] + 10.0f));
  }
  for (int i = t; i < 256; i += nthr) {
    a3p[i] = a3[i];
    o3p[i] = __fmul_rn(b3[i], exp2f((float)q3[i] + 10.0f));
  }
}

// ---------------- k01: pack x -> int8 (global x8p + LDS) then conv1 ----------------
__global__ __launch_bounds__(256) void k01_pack_conv1(
    const float* __restrict__ x,
    const int* __restrict__ w1p,
    const float* __restrict__ a1p, const float* __restrict__ o1p,
    int* __restrict__ x8p, int* __restrict__ y1p)
{
  __shared__ int ldsx[64 * 68];   // 17408 B

  int tid = threadIdx.x;

  // ---- Phase A: load + pack ----
  {
    int o = tid & 3;
    int p = tid >> 2;
    size_t pg = (size_t)blockIdx.x * 64 + p;
    int n = (int)(pg / HW);
    int pos = (int)(pg - (size_t)n * HW);
    const float* xb = x + ((size_t)n * 256 + o * 64) * HW + pos;

    float f[64];
#pragma unroll
    for (int k = 0; k < 64; ++k) f[k] = xb[(size_t)k * HW];
    __builtin_amdgcn_sched_barrier(0);  // all 64 loads before any consumer

    int4 ov[4];
#pragma unroll
    for (int g = 0; g < 4; ++g) {
      int wds[4];
#pragma unroll
      for (int wdi = 0; wdi < 4; ++wdi) {
        int c0 = g * 16 + wdi * 4;
        wds[wdi] = ((int)f[c0] & 0xFF) | (((int)f[c0 + 1] & 0xFF) << 8) |
                   (((int)f[c0 + 2] & 0xFF) << 16) | (((int)f[c0 + 3] & 0xFF) << 24);
      }
      ov[g].x = wds[0]; ov[g].y = wds[1]; ov[g].z = wds[2]; ov[g].w = wds[3];
    }

    int* gb = x8p + pg * 64 + o * 16;
#pragma unroll
    for (int g = 0; g < 4; ++g) ((int4*)gb)[g] = ov[g];
    int* lb = &ldsx[p * 68 + o * 16];
#pragma unroll
    for (int g = 0; g < 4; ++g) *(int4*)(lb + g * 4) = ov[g];
  }
  __syncthreads();

  // ---- Phase B: conv1 from LDS ----
  int lane = tid & 63;
  int s = __builtin_amdgcn_readfirstlane(tid >> 6);
  size_t pidx = (size_t)blockIdx.x * 64 + lane;

  int acc[16];
#pragma unroll
  for (int i = 0; i < 16; ++i) acc[i] = 0;

  const int* lx = &ldsx[lane * 68];
#pragma unroll
  for (int m = 0; m < 16; ++m) {
    int4 xm = *(const int4*)(lx + m * 4);
#pragma unroll
    for (int e = 0; e < 4; ++e) {
      int xv = e == 0 ? xm.x : (e == 1 ? xm.y : (e == 2 ? xm.z : xm.w));
      int cg = m * 4 + e;
      const int4* wr = (const int4*)(w1p + cg * 64 + s * 16);
#pragma unroll
      for (int c = 0; c < 4; ++c) {
        int4 wv = wr[c];
        acc[c * 4 + 0] = dot4i8(xv, wv.x, acc[c * 4 + 0]);
        acc[c * 4 + 1] = dot4i8(xv, wv.y, acc[c * 4 + 1]);
        acc[c * 4 + 2] = dot4i8(xv, wv.z, acc[c * 4 + 2]);
        acc[c * 4 + 3] = dot4i8(xv, wv.w, acc[c * 4 + 3]);
      }
    }
  }

  int op[4];
#pragma unroll
  for (int c = 0; c < 4; ++c) {
    int p = 0;
#pragma unroll
    for (int j = 0; j < 4; ++j) {
      int co = s * 16 + c * 4 + j;
      float r = bnq(a1p[co], o1p[co], acc[c * 4 + j]);
      int v = (int)r;
      if (v < 0) v = 0;  // relu
      p |= (v & 0xFF) << (8 * j);
    }
    op[c] = p;
  }
  int4 ov; ov.x = op[0]; ov.y = op[1]; ov.z = op[2]; ov.w = op[3];
  *(int4*)(y1p + pidx * 16 + s * 4) = ov;
}

// ---------------- k23: conv2+conv3 fused, P=2 positions/thread ----------------
// Block = 128 consecutive positions of ONE image (lane -> posA=p0l+lane,
// posB=posA+64); 25 blocks/image (last block: 64 pos, validB=0, uniform).
// Each weight s_load now feeds 2x the dot4s (conv2: 32/group, conv3: 128/c4)
// -> halves the lgkm stall per dot4 (R11 diagnosis: weight-load latency).
// Halo: 6 rows x 58 cols, stride 5 int4 (conflict-free). Residual loads
// hoisted before conv2 (only VMEM in flight there -> fully hidden).
// Grid 800 (%8==0): bijective XCD swizzle -> halo rows shared within an XCD L2.
__global__ __launch_bounds__(256) void k23_conv23(
    const int* __restrict__ y1p,
    const int* __restrict__ w2p,   // [s][tap][cg][cc]
    const float* __restrict__ a2p, const float* __restrict__ o2p,
    const int* __restrict__ w3p,
    const float* __restrict__ a3p, const float* __restrict__ o3p,
    const int* __restrict__ x8p,
    float* __restrict__ out)
{
  __shared__ int4 lds[6 * 58 * 5];   // halo: 1740 int4 = 27840 B
  __shared__ int ldsy[128 * 20];     // y2 tile: 10240 B

  // XCD swizzle: XCD k executes tiles 100k..100k+99 (contiguous halo sharing)
  int t0 = (blockIdx.x & 7) * 100 + (blockIdx.x >> 3);
  int n  = t0 / 25;
  int bl = t0 - n * 25;
  int p0l = bl * 128;
  int validB = (bl < 24);            // block-uniform

  int lane = threadIdx.x & 63;
  int s = __builtin_amdgcn_readfirstlane(threadIdx.x >> 6);
  int h0 = p0l / IMGW;

  // ---- stage halo rows h0-1 .. h0+4, zero-padded ----
  const int4* src = (const int4*)y1p;
  int tid = threadIdx.x;
#pragma unroll
  for (int i = 0; i < 6; ++i) {
    int idx = tid + i * 256;
    if (idx < 1392) {                 // 348 padded pos x 4 chunks
      int pp = idx >> 2;
      int chunk = idx & 3;
      int r = pp / 58;
      int col = pp - r * 58;
      int hh = h0 - 1 + r;
      int4 v = make_int4(0, 0, 0, 0);
      if ((unsigned)hh < 56u && col >= 1 && col <= 56)
        v = src[((size_t)n * HW + (size_t)hh * IMGW + (col - 1)) * 4 + chunk];
      lds[pp * 5 + chunk] = v;
    }
  }
  __syncthreads();

  // ---- hoisted residual loads: in flight during all of conv2 ----
  size_t pgA = (size_t)n * HW + p0l + lane;
  int4 rqA[4], rqB[4];
  {
    const int4* ra = (const int4*)(x8p + pgA * 64 + s * 16);
#pragma unroll
    for (int m = 0; m < 4; ++m) rqA[m] = ra[m];
    if (validB) {
      const int4* rb = (const int4*)(x8p + (pgA + 64) * 64 + s * 16);
#pragma unroll
      for (int m = 0; m < 4; ++m) rqB[m] = rb[m];
    } else {
#pragma unroll
      for (int m = 0; m < 4; ++m) rqB[m] = make_int4(0, 0, 0, 0);
    }
  }

  int posA = p0l + lane;
  int hA = posA / IMGW, wwA = posA - hA * IMGW;
  int posB = posA + 64;
  int hB = posB / IMGW, wwB = posB - hB * IMGW;
  int cA = (hA - h0 + 1) * 58 + (wwA + 1);
  int cB = (hB - h0 + 1) * 58 + (wwB + 1);

  // ---- conv2, both positions ----
  int accA[16], accB[16];
#pragma unroll
  for (int i = 0; i < 16; ++i) { accA[i] = 0; accB[i] = 0; }

  const int4* wq = (const int4*)w2p;

#pragma unroll
  for (int ky = 0; ky < 3; ++ky) {
#pragma unroll
    for (int kx = 0; kx < 3; ++kx) {
      int t = ky * 3 + kx;
      int lpA = cA + (ky - 1) * 58 + (kx - 1);
      int lpB = cB + (ky - 1) * 58 + (kx - 1);
      const int4* xtA = &lds[lpA * 5];
      const int4* xtB = &lds[lpB * 5];
      int4 xA0 = xtA[0], xA1 = xtA[1], xA2 = xtA[2], xA3 = xtA[3];
      int4 xB0 = xtB[0], xB1 = xtB[1], xB2 = xtB[2], xB3 = xtB[3];
      const int4* wt = wq + (s * 9 + t) * 64;
#pragma unroll
      for (int m = 0; m < 4; ++m) {
        int4 xmA = m == 0 ? xA0 : (m == 1 ? xA1 : (m == 2 ? xA2 : xA3));
        int4 xmB = m == 0 ? xB0 : (m == 1 ? xB1 : (m == 2 ? xB2 : xB3));
#pragma unroll
        for (int e = 0; e < 4; ++e) {
          int xvA = e == 0 ? xmA.x : (e == 1 ? xmA.y : (e == 2 ? xmA.z : xmA.w));
          int xvB = e == 0 ? xmB.x : (e == 1 ? xmB.y : (e == 2 ? xmB.z : xmB.w));
          const int4* wr = wt + (m * 4 + e) * 4;
#pragma unroll
          for (int cc = 0; cc < 4; ++cc) {
            int4 wv = wr[cc];
            accA[cc * 4 + 0] = dot4i8(xvA, wv.x, accA[cc * 4 + 0]);
            accA[cc * 4 + 1] = dot4i8(xvA, wv.y, accA[cc * 4 + 1]);
            accA[cc * 4 + 2] = dot4i8(xvA, wv.z, accA[cc * 4 + 2]);
            accA[cc * 4 + 3] = dot4i8(xvA, wv.w, accA[cc * 4 + 3]);
            accB[cc * 4 + 0] = dot4i8(xvB, wv.x, accB[cc * 4 + 0]);
            accB[cc * 4 + 1] = dot4i8(xvB, wv.y, accB[cc * 4 + 1]);
            accB[cc * 4 + 2] = dot4i8(xvB, wv.z, accB[cc * 4 + 2]);
            accB[cc * 4 + 3] = dot4i8(xvB, wv.w, accB[cc * 4 + 3]);
          }
        }
      }
    }
  }

  // ---- BN+relu -> y2 tiles in LDS ----
  {
    int opA[4], opB[4];
#pragma unroll
    for (int c = 0; c < 4; ++c) {
      int pA = 0, pB = 0;
#pragma unroll
      for (int j = 0; j < 4; ++j) {
        int co = s * 16 + c * 4 + j;
        float rA = bnq(a2p[co], o2p[co], accA[c * 4 + j]);
        int vA = (int)rA; if (vA < 0) vA = 0;
        pA |= (vA & 0xFF) << (8 * j);
        float rB = bnq(a2p[co], o2p[co], accB[c * 4 + j]);
        int vB = (int)rB; if (vB < 0) vB = 0;
        pB |= (vB & 0xFF) << (8 * j);
      }
      opA[c] = pA; opB[c] = pB;
    }
    int4 ovA; ovA.x = opA[0]; ovA.y = opA[1]; ovA.z = opA[2]; ovA.w = opA[3];
    int4 ovB; ovB.x = opB[0]; ovB.y = opB[1]; ovB.z = opB[2]; ovB.w = opB[3];
    *(int4*)(&ldsy[lane * 20 + s * 4]) = ovA;
    *(int4*)(&ldsy[(64 + lane) * 20 + s * 4]) = ovB;
  }
  __syncthreads();

  // ---- conv3 + residual + out, both positions; wave s -> out-ch s*64.. ----
  int xpA[16], xpB[16];
#pragma unroll
  for (int m = 0; m < 4; ++m) {
    int4 a4 = *(const int4*)(&ldsy[lane * 20 + m * 4]);
    xpA[m * 4 + 0] = a4.x; xpA[m * 4 + 1] = a4.y;
    xpA[m * 4 + 2] = a4.z; xpA[m * 4 + 3] = a4.w;
    int4 b4 = *(const int4*)(&ldsy[(64 + lane) * 20 + m * 4]);
    xpB[m * 4 + 0] = b4.x; xpB[m * 4 + 1] = b4.y;
    xpB[m * 4 + 2] = b4.z; xpB[m * 4 + 3] = b4.w;
  }

#pragma unroll
  for (int c4 = 0; c4 < 16; ++c4) {
    int co4 = s * 16 + c4;
    const int4* wr = ((const int4*)w3p) + co4 * 16;  // uniform -> s_load
    int aA0 = 0, aA1 = 0, aA2 = 0, aA3 = 0;
    int aB0 = 0, aB1 = 0, aB2 = 0, aB3 = 0;
#pragma unroll
    for (int cg = 0; cg < 16; ++cg) {
      int4 wv = wr[cg];
      aA0 = dot4i8(xpA[cg], wv.x, aA0);
      aA1 = dot4i8(xpA[cg], wv.y, aA1);
      aA2 = dot4i8(xpA[cg], wv.z, aA2);
      aA3 = dot4i8(xpA[cg], wv.w, aA3);
      aB0 = dot4i8(xpB[cg], wv.x, aB0);
      aB1 = dot4i8(xpB[cg], wv.y, aB1);
      aB2 = dot4i8(xpB[cg], wv.z, aB2);
      aB3 = dot4i8(xpB[cg], wv.w, aB3);
    }

    int ipA = (c4 & 3) == 0 ? rqA[c4 >> 2].x : ((c4 & 3) == 1 ? rqA[c4 >> 2].y
            : ((c4 & 3) == 2 ? rqA[c4 >> 2].z : rqA[c4 >> 2].w));
    int ipB = (c4 & 3) == 0 ? rqB[c4 >> 2].x : ((c4 & 3) == 1 ? rqB[c4 >> 2].y
            : ((c4 & 3) == 2 ? rqB[c4 >> 2].z : rqB[c4 >> 2].w));

    float* obA = out + ((size_t)n * 256 + (size_t)co4 * 4) * HW + posA;
    int accsA[4] = {aA0, aA1, aA2, aA3};
    int accsB[4] = {aB0, aB1, aB2, aB3};
#pragma unroll
    for (int j = 0; j < 4; ++j) {
      int co = co4 * 4 + j;
      float rA = bnq(a3p[co], o3p[co], accsA[j]);
      int idA = (int)(int8_t)(ipA >> (8 * j));
      int vA = (int)rA + idA;
      vA = vA > 127 ? 127 : vA;
      vA = vA < 0 ? 0 : vA;
      obA[(size_t)j * HW] = (float)vA;
      if (validB) {
        float rB = bnq(a3p[co], o3p[co], accsB[j]);
        int idB = (int)(int8_t)(ipB >> (8 * j));
        int vB = (int)rB + idB;
        vB = vB > 127 ? 127 : vB;
        vB = vB < 0 ? 0 : vB;
        obA[(size_t)j * HW + 64] = (float)vB;   // posB = posA + 64
      }
    }
  }
}

extern "C" void kernel_launch(void* const* d_in, const int* in_sizes, int n_in,
                              void* d_out, int out_size, void* d_ws, size_t ws_size,
                              hipStream_t stream) {
  const float* x  = (const float*)d_in[0];
  const int*   s1 = (const int*)d_in[1];
  const int*   m1 = (const int*)d_in[2];
  const float* a1 = (const float*)d_in[3];
  const float* b1 = (const float*)d_in[4];
  const int*   q1 = (const int*)d_in[5];
  const int*   s2 = (const int*)d_in[6];
  const int*   m2 = (const int*)d_in[7];
  const float* a2 = (const float*)d_in[8];
  const float* b2 = (const float*)d_in[9];
  const int*   q2 = (const int*)d_in[10];
  const int*   s3 = (const int*)d_in[11];
  const int*   m3 = (const int*)d_in[12];
  const float* a3 = (const float*)d_in[13];
  const float* b3 = (const float*)d_in[14];
  const int*   q3 = (const int*)d_in[15];

  char* ws = (char*)d_ws;
  int* w1p = (int*)(ws + 0);        // 16384 B
  int* w2p = (int*)(ws + 16384);    // 36864 B
  int* w3p = (int*)(ws + 53248);    // 16384 B
  float* a1p = (float*)(ws + 69632);
  float* o1p = (float*)(ws + 69888);
  float* a2p = (float*)(ws + 70144);
  float* o2p = (float*)(ws + 70400);
  float* a3p = (float*)(ws + 70656);
  float* o3p = (float*)(ws + 71680);
  int* y1p = (int*)(ws + 73728);                       // 6,422,528 B (packed [n][pos][16])
  int* x8p = (int*)(ws + 73728 + 6422528);             // 25,690,112 B (packed [n][pos][64])

  prep_kernel<<<64, 256, 0, stream>>>(s1, m1, a1, b1, q1,
                                      s2, m2, a2, b2, q2,
                                      s3, m3, a3, b3, q3,
                                      w1p, w2p, w3p,
                                      a1p, o1p, a2p, o2p, a3p, o3p);

  k01_pack_conv1<<<(NIMG * HW) / 64, 256, 0, stream>>>(x, w1p, a1p, o1p, x8p, y1p);
  // 25 blocks per image (24 x 128-pos + 1 x 64-pos), 32 images = 800 blocks
  k23_conv23<<<800, 256, 0, stream>>>(y1p, w2p, a2p, o2p,
                                      w3p, a3p, o3p, x8p,
                                      (float*)d_out);
}

// Round 13
// 107.026 us; speedup vs baseline: 1.1339x; 1.1339x over previous
//
#include <hip/hip_runtime.h>
#include <stdint.h>

#define HW 3136
#define IMGW 56
#define NIMG 32

static __device__ __forceinline__ int dot4i8(int a, int b, int c) {
#if __has_builtin(__builtin_amdgcn_sdot4)
  return __builtin_amdgcn_sdot4(a, b, c, false);
#else
  c += (int)(int8_t)(a      ) * (int)(int8_t)(b      );
  c += (int)(int8_t)(a >>  8) * (int)(int8_t)(b >>  8);
  c += (int)(int8_t)(a >> 16) * (int)(int8_t)(b >> 16);
  c += (int)(int8_t)(a >> 24) * (int)(int8_t)(b >> 24);
  return c;
#endif
}

// BN: round((alpha*acc + off) * 2^-10), clamp to [-128,127]. Exact f32 ops,
// no contraction (matches numpy mul/add/round-half-even chain bit-exactly).
static __device__ __forceinline__ float bnq(float alpha, float off, int acc) {
  float t = __fmul_rn(alpha, (float)acc);
  t = __fadd_rn(t, off);
  t = __fmul_rn(t, 0x1p-10f);
  float r = rintf(t);
  return fminf(fmaxf(r, -128.0f), 127.0f);
}

// ---------------- prep: pack weights + fold BN constants ----------------
__global__ void prep_kernel(
    const int* __restrict__ s1, const int* __restrict__ m1,
    const float* __restrict__ a1, const float* __restrict__ b1, const int* __restrict__ q1,
    const int* __restrict__ s2, const int* __restrict__ m2,
    const float* __restrict__ a2, const float* __restrict__ b2, const int* __restrict__ q2,
    const int* __restrict__ s3, const int* __restrict__ m3,
    const float* __restrict__ a3, const float* __restrict__ b3, const int* __restrict__ q3,
    int* __restrict__ w1p, int* __restrict__ w2p, int* __restrict__ w3p,
    float* __restrict__ a1p, float* __restrict__ o1p,
    float* __restrict__ a2p, float* __restrict__ o2p,
    float* __restrict__ a3p, float* __restrict__ o3p)
{
  int t = blockIdx.x * blockDim.x + threadIdx.x;
  int nthr = gridDim.x * blockDim.x;

  // w1p[cg*64 + co] packs input channels cg*4..cg*4+3 for output co (conv1: 64x256)
  for (int i = t; i < 64 * 64; i += nthr) {
    int cg = i >> 6, co = i & 63;
    int p = 0;
    for (int j = 0; j < 4; ++j) {
      int ci = cg * 4 + j;
      int idx = co * 256 + ci;
      int w = m1[idx] * (1 << s1[idx]);
      p |= (w & 0xFF) << (8 * j);
    }
    w1p[i] = p;
  }
  // w2p layout: i = ((s*9+tap)*16+cg)*16 + cc*4 + j
  for (int i = t; i < 4 * 9 * 16 * 16; i += nthr) {
    int j = i & 3;
    int cc = (i >> 2) & 3;
    int cg = (i >> 4) & 15;
    int rest = i >> 8;        // s*9 + tap
    int tap = rest % 9;
    int s = rest / 9;
    int co = s * 16 + cc * 4 + j;
    int ky = tap / 3, kx = tap % 3;
    int p = 0;
    for (int jj = 0; jj < 4; ++jj) {
      int ci = cg * 4 + jj;
      int idx = ((co * 64 + ci) * 3 + ky) * 3 + kx;
      int w = m2[idx] * (1 << s2[idx]);
      p |= (w & 0xFF) << (8 * jj);
    }
    w2p[i] = p;
  }
  // w3p[(co4*16+cg)*4 + j]
  for (int i = t; i < 64 * 16 * 4; i += nthr) {
    int j = i & 3;
    int cg = (i >> 2) & 15;
    int co4 = i >> 6;
    int co = co4 * 4 + j;
    int p = 0;
    for (int jj = 0; jj < 4; ++jj) {
      int ci = cg * 4 + jj;
      int idx = co * 64 + ci;
      int w = m3[idx] * (1 << s3[idx]);
      p |= (w & 0xFF) << (8 * jj);
    }
    w3p[i] = p;
  }
  for (int i = t; i < 64; i += nthr) {
    a1p[i] = a1[i];
    o1p[i] = __fmul_rn(b1[i], exp2f((float)q1[i] + 10.0f));
    a2p[i] = a2[i];
    o2p[i] = __fmul_rn(b2[i], exp2f((float)q2[i] + 10.0f));
  }
  for (int i = t; i < 256; i += nthr) {
    a3p[i] = a3[i];
    o3p[i] = __fmul_rn(b3[i], exp2f((float)q3[i] + 10.0f));
  }
}

// ---------------- k01: pack x -> int8 (global x8p + LDS) then conv1 ----------------
// Phase B conv1 is ROLLED (16-iter m loop, ~0.7 KB body) to keep total kernel
// text < I$; inner 64-dot4 body stays unrolled for register blocking.
__global__ __launch_bounds__(256) void k01_pack_conv1(
    const float* __restrict__ x,
    const int* __restrict__ w1p,
    const float* __restrict__ a1p, const float* __restrict__ o1p,
    int* __restrict__ x8p, int* __restrict__ y1p)
{
  __shared__ int ldsx[64 * 68];   // 17408 B

  int tid = threadIdx.x;

  // ---- Phase A: load + pack ----
  {
    int o = tid & 3;
    int p = tid >> 2;
    size_t pg = (size_t)blockIdx.x * 64 + p;
    int n = (int)(pg / HW);
    int pos = (int)(pg - (size_t)n * HW);
    const float* xb = x + ((size_t)n * 256 + o * 64) * HW + pos;

    float f[64];
#pragma unroll
    for (int k = 0; k < 64; ++k) f[k] = xb[(size_t)k * HW];
    __builtin_amdgcn_sched_barrier(0);  // all 64 loads before any consumer

    int4 ov[4];
#pragma unroll
    for (int g = 0; g < 4; ++g) {
      int wds[4];
#pragma unroll
      for (int wdi = 0; wdi < 4; ++wdi) {
        int c0 = g * 16 + wdi * 4;
        wds[wdi] = ((int)f[c0] & 0xFF) | (((int)f[c0 + 1] & 0xFF) << 8) |
                   (((int)f[c0 + 2] & 0xFF) << 16) | (((int)f[c0 + 3] & 0xFF) << 24);
      }
      ov[g].x = wds[0]; ov[g].y = wds[1]; ov[g].z = wds[2]; ov[g].w = wds[3];
    }

    int* gb = x8p + pg * 64 + o * 16;
#pragma unroll
    for (int g = 0; g < 4; ++g) ((int4*)gb)[g] = ov[g];
    int* lb = &ldsx[p * 68 + o * 16];
#pragma unroll
    for (int g = 0; g < 4; ++g) *(int4*)(lb + g * 4) = ov[g];
  }
  __syncthreads();

  // ---- Phase B: conv1 from LDS (rolled m loop) ----
  int lane = tid & 63;
  int s = __builtin_amdgcn_readfirstlane(tid >> 6);
  size_t pidx = (size_t)blockIdx.x * 64 + lane;

  int acc[16];
#pragma unroll
  for (int i = 0; i < 16; ++i) acc[i] = 0;

  const int* lx = &ldsx[lane * 68];
#pragma clang loop unroll(disable)
  for (int m = 0; m < 16; ++m) {
    int4 xm = *(const int4*)(lx + m * 4);
#pragma unroll
    for (int e = 0; e < 4; ++e) {
      int xv = e == 0 ? xm.x : (e == 1 ? xm.y : (e == 2 ? xm.z : xm.w));
      const int4* wr = (const int4*)(w1p + (m * 4 + e) * 64 + s * 16);
#pragma unroll
      for (int c = 0; c < 4; ++c) {
        int4 wv = wr[c];
        acc[c * 4 + 0] = dot4i8(xv, wv.x, acc[c * 4 + 0]);
        acc[c * 4 + 1] = dot4i8(xv, wv.y, acc[c * 4 + 1]);
        acc[c * 4 + 2] = dot4i8(xv, wv.z, acc[c * 4 + 2]);
        acc[c * 4 + 3] = dot4i8(xv, wv.w, acc[c * 4 + 3]);
      }
    }
  }

  int op[4];
#pragma unroll
  for (int c = 0; c < 4; ++c) {
    int p = 0;
#pragma unroll
    for (int j = 0; j < 4; ++j) {
      int co = s * 16 + c * 4 + j;
      float r = bnq(a1p[co], o1p[co], acc[c * 4 + j]);
      int v = (int)r;
      if (v < 0) v = 0;  // relu
      p |= (v & 0xFF) << (8 * j);
    }
    op[c] = p;
  }
  int4 ov; ov.x = op[0]; ov.y = op[1]; ov.z = op[2]; ov.w = op[3];
  *(int4*)(y1p + pidx * 16 + s * 4) = ov;
}

// ---------------- k23: conv2 (LDS halo) -> y2 in LDS -> conv3 + residual ----------------
// R13: ROLLED loops to fit I$ (R12 diagnosis: ~70 KB unrolled text vs 32 KB
// I$ -> instruction-supply bound, VALUBusy pinned ~35% across all memory
// fixes). conv2 = 9-iter tap loop (~0.7 KB body); conv3 = 4 static copies
// (keeps residual rq[m] statically indexed, rule #20) x rolled 4-iter cc
// loop. P=1, 64-pos tiles, halo stride-5-int4 (conflict-free), bijective
// XCD swizzle (1568 = 8*196), hoisted residual loads.
__global__ __launch_bounds__(256) void k23_conv23(
    const int* __restrict__ y1p,
    const int* __restrict__ w2p,   // [s][tap][cg][cc]
    const float* __restrict__ a2p, const float* __restrict__ o2p,
    const int* __restrict__ w3p,
    const float* __restrict__ a3p, const float* __restrict__ o3p,
    const int* __restrict__ x8p,
    float* __restrict__ out)
{
  __shared__ int4 lds[4 * 58 * 5];   // halo: 18560 B
  __shared__ int ldsy[64 * 20];      // y2 tile: 5120 B

  // bijective XCD swizzle: XCD k runs tiles 196k..196k+195 (contiguous)
  int t0 = (blockIdx.x & 7) * 196 + (blockIdx.x >> 3);
  int n = t0 / 49;
  int bl = t0 - n * 49;
  int p0l = bl * 64;

  int lane = threadIdx.x & 63;
  int s = __builtin_amdgcn_readfirstlane(threadIdx.x >> 6);
  int h0 = p0l / IMGW;

  // ---- stage halo rows h0-1..h0+2, zero-padded; lds[pp*5 + chunk] ----
  const int4* src = (const int4*)y1p;
  int tid = threadIdx.x;
#pragma unroll
  for (int i = 0; i < 4; ++i) {
    int idx = tid + i * 256;
    if (idx < 928) {
      int pp = idx >> 2;
      int chunk = idx & 3;
      int r = pp / 58;
      int col = pp - r * 58;
      int hh = h0 - 1 + r;
      int4 v = make_int4(0, 0, 0, 0);
      if ((unsigned)hh < 56u && col >= 1 && col <= 56)
        v = src[((size_t)n * HW + (size_t)hh * IMGW + (col - 1)) * 4 + chunk];
      lds[pp * 5 + chunk] = v;
    }
  }
  __syncthreads();

  // ---- hoisted residual loads (in flight under conv2) ----
  size_t pg = (size_t)n * HW + p0l + lane;
  int4 rq0, rq1, rq2, rq3;
  {
    const int4* ra = (const int4*)(x8p + pg * 64 + s * 16);
    rq0 = ra[0]; rq1 = ra[1]; rq2 = ra[2]; rq3 = ra[3];
  }

  int posl = p0l + lane;
  int h = posl / IMGW;
  int w = posl - h * IMGW;
  int center = (h - h0 + 1) * 58 + (w + 1);

  // ---- conv2: rolled 9-tap loop ----
  int acc[16];
#pragma unroll
  for (int i = 0; i < 16; ++i) acc[i] = 0;

  const int4* wq = (const int4*)w2p;

#pragma clang loop unroll(disable)
  for (int t = 0; t < 9; ++t) {
    int ky = t / 3;            // scalar (uniform) arithmetic
    int kx = t - ky * 3;
    int lp2 = center + (ky - 1) * 58 + (kx - 1);
    const int4* xt = &lds[lp2 * 5];
    int4 x0 = xt[0], x1 = xt[1], x2 = xt[2], x3 = xt[3];
    const int4* wt = wq + (s * 9 + t) * 64;
#pragma unroll
    for (int m = 0; m < 4; ++m) {
      int4 xm = m == 0 ? x0 : (m == 1 ? x1 : (m == 2 ? x2 : x3));
#pragma unroll
      for (int e = 0; e < 4; ++e) {
        int xv = e == 0 ? xm.x : (e == 1 ? xm.y : (e == 2 ? xm.z : xm.w));
        const int4* wr = wt + (m * 4 + e) * 4;
#pragma unroll
        for (int cc = 0; cc < 4; ++cc) {
          int4 wv = wr[cc];
          acc[cc * 4 + 0] = dot4i8(xv, wv.x, acc[cc * 4 + 0]);
          acc[cc * 4 + 1] = dot4i8(xv, wv.y, acc[cc * 4 + 1]);
          acc[cc * 4 + 2] = dot4i8(xv, wv.z, acc[cc * 4 + 2]);
          acc[cc * 4 + 3] = dot4i8(xv, wv.w, acc[cc * 4 + 3]);
        }
      }
    }
  }

  // ---- BN+relu -> y2 tile in LDS ----
  {
    int op[4];
#pragma unroll
    for (int c = 0; c < 4; ++c) {
      int p = 0;
#pragma unroll
      for (int j = 0; j < 4; ++j) {
        int co = s * 16 + c * 4 + j;
        float r = bnq(a2p[co], o2p[co], acc[c * 4 + j]);
        int v = (int)r;
        if (v < 0) v = 0;
        p |= (v & 0xFF) << (8 * j);
      }
      op[c] = p;
    }
    int4 ov; ov.x = op[0]; ov.y = op[1]; ov.z = op[2]; ov.w = op[3];
    *(int4*)(&ldsy[lane * 20 + s * 4]) = ov;
  }
  __syncthreads();

  // ---- conv3 + residual + out ----
  int xp[16];
#pragma unroll
  for (int m = 0; m < 4; ++m) {
    int4 xm = *(const int4*)(&ldsy[lane * 20 + m * 4]);
    xp[m * 4 + 0] = xm.x;
    xp[m * 4 + 1] = xm.y;
    xp[m * 4 + 2] = xm.z;
    xp[m * 4 + 3] = xm.w;
  }

#pragma unroll
  for (int m = 0; m < 4; ++m) {       // static: rq[m] stays in registers
    int4 rqm = m == 0 ? rq0 : (m == 1 ? rq1 : (m == 2 ? rq2 : rq3));
#pragma clang loop unroll(disable)
    for (int cc = 0; cc < 4; ++cc) {  // rolled: 4 iters x ~0.7 KB body
      int c4 = m * 4 + cc;
      int co4 = s * 16 + c4;
      const int4* wr = ((const int4*)w3p) + co4 * 16;  // uniform -> s_load
      int ac0 = 0, ac1 = 0, ac2 = 0, ac3 = 0;
#pragma unroll
      for (int cg = 0; cg < 16; ++cg) {
        int4 wv = wr[cg];
        ac0 = dot4i8(xp[cg], wv.x, ac0);
        ac1 = dot4i8(xp[cg], wv.y, ac1);
        ac2 = dot4i8(xp[cg], wv.z, ac2);
        ac3 = dot4i8(xp[cg], wv.w, ac3);
      }

      int ip = cc == 0 ? rqm.x : (cc == 1 ? rqm.y : (cc == 2 ? rqm.z : rqm.w));

      float* ob = out + ((size_t)n * 256 + (size_t)co4 * 4) * HW + posl;
      int accs[4] = {ac0, ac1, ac2, ac3};
#pragma unroll
      for (int j = 0; j < 4; ++j) {
        int co = co4 * 4 + j;
        float r = bnq(a3p[co], o3p[co], accs[j]);
        int id = (int)(int8_t)(ip >> (8 * j));
        int v = (int)r + id;
        v = v > 127 ? 127 : v;
        v = v < 0 ? 0 : v;  // clamp(-128,..) then relu => max(0, min(127, .))
        ob[(size_t)j * HW] = (float)v;
      }
    }
  }
}

extern "C" void kernel_launch(void* const* d_in, const int* in_sizes, int n_in,
                              void* d_out, int out_size, void* d_ws, size_t ws_size,
                              hipStream_t stream) {
  const float* x  = (const float*)d_in[0];
  const int*   s1 = (const int*)d_in[1];
  const int*   m1 = (const int*)d_in[2];
  const float* a1 = (const float*)d_in[3];
  const float* b1 = (const float*)d_in[4];
  const int*   q1 = (const int*)d_in[5];
  const int*   s2 = (const int*)d_in[6];
  const int*   m2 = (const int*)d_in[7];
  const float* a2 = (const float*)d_in[8];
  const float* b2 = (const float*)d_in[9];
  const int*   q2 = (const int*)d_in[10];
  const int*   s3 = (const int*)d_in[11];
  const int*   m3 = (const int*)d_in[12];
  const float* a3 = (const float*)d_in[13];
  const float* b3 = (const float*)d_in[14];
  const int*   q3 = (const int*)d_in[15];

  char* ws = (char*)d_ws;
  int* w1p = (int*)(ws + 0);        // 16384 B
  int* w2p = (int*)(ws + 16384);    // 36864 B
  int* w3p = (int*)(ws + 53248);    // 16384 B
  float* a1p = (float*)(ws + 69632);
  float* o1p = (float*)(ws + 69888);
  float* a2p = (float*)(ws + 70144);
  float* o2p = (float*)(ws + 70400);
  float* a3p = (float*)(ws + 70656);
  float* o3p = (float*)(ws + 71680);
  int* y1p = (int*)(ws + 73728);                       // 6,422,528 B (packed [n][pos][16])
  int* x8p = (int*)(ws + 73728 + 6422528);             // 25,690,112 B (packed [n][pos][64])

  prep_kernel<<<64, 256, 0, stream>>>(s1, m1, a1, b1, q1,
                                      s2, m2, a2, b2, q2,
                                      s3, m3, a3, b3, q3,
                                      w1p, w2p, w3p,
                                      a1p, o1p, a2p, o2p, a3p, o3p);

  k01_pack_conv1<<<(NIMG * HW) / 64, 256, 0, stream>>>(x, w1p, a1p, o1p, x8p, y1p);
  k23_conv23<<<(NIMG * HW) / 64, 256, 0, stream>>>(y1p, w2p, a2p, o2p,
                                                   w3p, a3p, o3p, x8p,
                                                   (float*)d_out);
}